// Round 2
// baseline (225.704 us; speedup 1.0000x reference)
//
#include <hip/hip_runtime.h>
#include <hip/hip_bf16.h>

// Problem constants (fixed by the reference file)
#define N_ELEM   4194304
#define NUM_IDS  262144
#define M_CAP    (NUM_IDS + 1)   // 262145
#define L_CAP    128

// Scan geometry: 256 blocks x 256 threads x 4 ids = 262144
#define SCAN_BLOCKS 256

// ---------------------------------------------------------------------------
// Kernel 1: run boundary detection. Sorted ids => one run per present id.
// start_arr[v] = first index of id v, end_arr[v] = one-past-last, present[v]=1.
// ---------------------------------------------------------------------------
__global__ void k_boundaries(const int* __restrict__ ids,
                             int* __restrict__ start_arr,
                             int* __restrict__ end_arr,
                             int* __restrict__ present,
                             int n) {
    int i = blockIdx.x * blockDim.x + threadIdx.x;
    if (i >= n) return;
    int v = ids[i];
    if (i == 0 || ids[i - 1] != v) {   // run start
        start_arr[v] = i;
        present[v]   = 1;
    }
    if (i == n - 1 || ids[i + 1] != v) // run end
        end_arr[v] = i + 1;
}

// ---------------------------------------------------------------------------
// Kernel 2a: per-block exclusive scan of present[]. Block b covers 1024 ids.
// ---------------------------------------------------------------------------
__global__ void k_scan_blocks(const int* __restrict__ present,
                              int* __restrict__ rank_local,
                              int* __restrict__ partial) {
    int b = blockIdx.x, t = threadIdx.x;
    int4 p = ((const int4*)present)[b * 256 + t];
    int s1 = p.x + p.y;
    int s2 = s1 + p.z;
    int tsum = s2 + p.w;

    __shared__ int sm[256];
    sm[t] = tsum;
    __syncthreads();
    for (int off = 1; off < 256; off <<= 1) {
        int val = (t >= off) ? sm[t - off] : 0;
        __syncthreads();
        if (t >= off) sm[t] += val;
        __syncthreads();
    }
    int excl = sm[t] - tsum;  // exclusive prefix of this thread's 4 ids

    int4 r;
    r.x = excl;
    r.y = excl + p.x;
    r.z = excl + s1;
    r.w = excl + s2;
    ((int4*)rank_local)[b * 256 + t] = r;

    if (t == 255) partial[b] = sm[255];
}

// ---------------------------------------------------------------------------
// Kernel 2b: scan the 256 block partials; offsets[] exclusive; total = #runs.
// ---------------------------------------------------------------------------
__global__ void k_scan_partials(const int* __restrict__ partial,
                                int* __restrict__ offsets,
                                int* __restrict__ num_runs) {
    int t = threadIdx.x;
    int v = partial[t];
    __shared__ int sm[256];
    sm[t] = v;
    __syncthreads();
    for (int off = 1; off < 256; off <<= 1) {
        int val = (t >= off) ? sm[t - off] : 0;
        __syncthreads();
        if (t >= off) sm[t] += val;
        __syncthreads();
    }
    offsets[t] = sm[t] - v;
    if (t == 255) num_runs[0] = sm[255];
}

// ---------------------------------------------------------------------------
// Kernel 2c: scatter inverse rank map: row_id[rank[v]] = v for present ids.
// ---------------------------------------------------------------------------
__global__ void k_scatter(const int* __restrict__ present,
                          const int* __restrict__ rank_local,
                          const int* __restrict__ offsets,
                          int* __restrict__ row_id) {
    int v = blockIdx.x * blockDim.x + threadIdx.x;
    if (v >= NUM_IDS) return;
    if (present[v])
        row_id[rank_local[v] + offsets[v >> 10]] = v;
}

// ---------------------------------------------------------------------------
// Kernel 3: one wave per output row m. FLOAT32 output buffer:
//   out[0 .. M_CAP)              : run_ids as float ((float)id, or -1.0f)
//   out[M_CAP + m*L_CAP ...]     : row m's features (bit-exact float32 copy)
// m <  num_runs-1 : valid row;  m >= num_runs-1 : -1 id, zero row
// Lane l writes row elements l and l+64 -> each wave store = 256 B contiguous.
// ---------------------------------------------------------------------------
__global__ void k_write_rows(const int* __restrict__ row_id,
                             const int* __restrict__ start_arr,
                             const int* __restrict__ end_arr,
                             const int* __restrict__ num_runs_ptr,
                             const float* __restrict__ feat,
                             float* __restrict__ out) {
    int wave = threadIdx.x >> 6;
    int lane = threadIdx.x & 63;
    int m = blockIdx.x * 4 + wave;
    if (m >= M_CAP) return;

    int num_valid = num_runs_ptr[0] - 1;
    float* row = out + M_CAP + (size_t)m * L_CAP;

    if (m < num_valid) {
        int v = row_id[m];
        int s = start_arr[v];
        int len = end_arr[v] - s;
        if (len > L_CAP) len = L_CAP;
        if (lane == 0) out[m] = (float)v;
        float e0 = (lane < len)      ? feat[s + lane]      : 0.0f;
        float e1 = (lane + 64 < len) ? feat[s + lane + 64] : 0.0f;
        row[lane]      = e0;
        row[lane + 64] = e1;
    } else {
        if (lane == 0) out[m] = -1.0f;
        row[lane]      = 0.0f;
        row[lane + 64] = 0.0f;
    }
}

// ---------------------------------------------------------------------------
extern "C" void kernel_launch(void* const* d_in, const int* in_sizes, int n_in,
                              void* d_out, int out_size, void* d_ws, size_t ws_size,
                              hipStream_t stream) {
    const int n = in_sizes[0];                 // 4194304
    const int* ids = (const int*)d_in[0];      // int32
    const float* feat = (const float*)d_in[1]; // float32
    float* out = (float*)d_out;                // float32, 262145 + 262145*128

    // Workspace layout (ints); total ~5.25 MB
    int* ws        = (int*)d_ws;
    int* start_arr = ws;                      // NUM_IDS
    int* end_arr   = start_arr + NUM_IDS;     // NUM_IDS
    int* present   = end_arr   + NUM_IDS;     // NUM_IDS
    int* rank_loc  = present   + NUM_IDS;     // NUM_IDS
    int* partial   = rank_loc  + NUM_IDS;     // 256
    int* offsets   = partial   + 256;         // 256
    int* num_runs  = offsets   + 256;         // 1 (padded to 4)
    int* row_id    = num_runs  + 4;           // M_CAP

    // present[] must start zeroed (ws is re-poisoned 0xAA each launch)
    hipMemsetAsync(present, 0, NUM_IDS * sizeof(int), stream);

    k_boundaries<<<(n + 255) / 256, 256, 0, stream>>>(ids, start_arr, end_arr, present, n);
    k_scan_blocks<<<SCAN_BLOCKS, 256, 0, stream>>>(present, rank_loc, partial);
    k_scan_partials<<<1, 256, 0, stream>>>(partial, offsets, num_runs);
    k_scatter<<<NUM_IDS / 256, 256, 0, stream>>>(present, rank_loc, offsets, row_id);
    k_write_rows<<<(M_CAP + 3) / 4, 256, 0, stream>>>(row_id, start_arr, end_arr,
                                                      num_runs, feat, out);
}